// Round 2
// baseline (767.210 us; speedup 1.0000x reference)
//
#include <hip/hip_runtime.h>

typedef unsigned short ushort_t;
typedef __attribute__((ext_vector_type(4))) ushort_t ushort4_t;
typedef __attribute__((ext_vector_type(8))) short short8;
typedef __attribute__((ext_vector_type(4))) float f32x4;

#define TOKENS  4096
#define H_DIM   1024
#define HFF_DIM 4096
#define NEXP    8

// round-to-nearest-even f32 -> bf16
__device__ __forceinline__ ushort_t f2b(float f) {
    union { float f; unsigned u; } v; v.f = f;
    unsigned r = v.u + 0x7fffu + ((v.u >> 16) & 1u);
    return (ushort_t)(r >> 16);
}

// jax.nn.gelu default: approximate=True (tanh form)
__device__ __forceinline__ float gelu_tanh(float x) {
    float u = 0.7978845608028654f * (x + 0.044715f * x * x * x);
    return 0.5f * x * (1.0f + tanhf(u));
}

// async global->LDS, 16B per lane; LDS dest = wave-uniform base + lane*16
__device__ __forceinline__ void load_lds16(const void* g, void* l) {
    __builtin_amdgcn_global_load_lds(
        (const __attribute__((address_space(1))) unsigned int*)g,
        (__attribute__((address_space(3))) unsigned int*)l, 16, 0, 0);
}

// ---------------- routing ----------------
__global__ void route_kernel(const float* __restrict__ probs,
                             const int* __restrict__ idx,
                             int* __restrict__ count,
                             int* __restrict__ token_id,
                             float* __restrict__ gate) {
    int t = blockIdx.x * blockDim.x + threadIdx.x;
    if (t >= TOKENS) return;
    int i0 = idx[t * 2 + 0];
    int i1 = idx[t * 2 + 1];
    float p0 = probs[t * 2 + 0];
    float p1 = probs[t * 2 + 1];
    if (i0 == i1) {
        float p = fmaxf(p0, p1);
        int pos = atomicAdd(&count[i0], 1);
        token_id[i0 * TOKENS + pos] = t;
        gate[i0 * TOKENS + pos] = p;
    } else {
        int pos = atomicAdd(&count[i0], 1);
        token_id[i0 * TOKENS + pos] = t;
        gate[i0 * TOKENS + pos] = p0;
        pos = atomicAdd(&count[i1], 1);
        token_id[i1 * TOKENS + pos] = t;
        gate[i1 * TOKENS + pos] = p1;
    }
}

__global__ void prefix_kernel(const int* __restrict__ count, int* __restrict__ offsets) {
    if (threadIdx.x == 0 && blockIdx.x == 0) {
        int acc = 0;
        for (int e = 0; e < NEXP; ++e) { offsets[e] = acc; acc += count[e]; }
        offsets[NEXP] = acc;
    }
}

// ---------------- f32 -> bf16 cast (memory-bound) ----------------
__global__ void cast_kernel(const float* __restrict__ in, ushort_t* __restrict__ out, int n4) {
    int i = blockIdx.x * blockDim.x + threadIdx.x;
    int stride = gridDim.x * blockDim.x;
    for (; i < n4; i += stride) {
        float4 v = ((const float4*)in)[i];
        ushort4_t o;
        o.x = f2b(v.x); o.y = f2b(v.y); o.z = f2b(v.z); o.w = f2b(v.w);
        ((ushort4_t*)out)[i] = o;
    }
}

// ================= FAST PATH (m97-style, bf16 precast) =================
// LDS layout per tile: [c(4 k-chunks)][row(128)][8 bf16] -- linear in lane
// order for global_load_lds, bank-balanced for ds_read_b128.

// GEMM1: h[slot] = gelu(xb[tok] . W1b[e]^T), bf16 out. 128x128 tile, BK=32.
__global__ __launch_bounds__(256) void gemm1_fast(
        const ushort_t* __restrict__ xb, const ushort_t* __restrict__ W1b,
        const int* __restrict__ count, const int* __restrict__ offsets,
        const int* __restrict__ token_id, ushort_t* __restrict__ h) {
    const int e = blockIdx.z;
    const int cnt = count[e];
    const int mt = blockIdx.y;
    if (mt * 128 >= cnt) return;
    const int nt = blockIdx.x;
    const int base = offsets[e];

    __shared__ __align__(16) ushort_t As[4096];  // 8 KB
    __shared__ __align__(16) ushort_t Bs[4096];

    const int tid = threadIdx.x;
    const int row = tid & 127;
    const int c0 = tid >> 7;  // 0..1 (issue 1 uses c0+2)

    int am = mt * 128 + row;
    int amc = am < cnt ? am : (cnt - 1);   // clamp: garbage rows discarded later
    const int tok = token_id[e * TOKENS + amc];
    const ushort_t* aptr = xb + (size_t)tok * H_DIM + c0 * 8;
    const ushort_t* bptr = W1b + (size_t)e * HFF_DIM * H_DIM
                           + (size_t)(nt * 128 + row) * H_DIM + c0 * 8;

    ushort_t* aL0 = As + tid * 8;
    ushort_t* aL1 = As + tid * 8 + 2048;
    ushort_t* bL0 = Bs + tid * 8;
    ushort_t* bL1 = Bs + tid * 8 + 2048;

    const int lane = tid & 63;
    const int wave = tid >> 6;
    const int wm = (wave >> 1) << 6;
    const int wn = (wave & 1) << 6;
    const int lr = lane & 15;
    const int lq = lane >> 4;

    f32x4 acc[4][4];
#pragma unroll
    for (int mi = 0; mi < 4; ++mi)
#pragma unroll
        for (int ni = 0; ni < 4; ++ni)
            acc[mi][ni] = (f32x4){0.f, 0.f, 0.f, 0.f};

    for (int k0 = 0; k0 < H_DIM; k0 += 32) {
        __syncthreads();
        load_lds16(aptr + k0, aL0);
        load_lds16(aptr + k0 + 16, aL1);
        load_lds16(bptr + k0, bL0);
        load_lds16(bptr + k0 + 16, bL1);
        __syncthreads();

        short8 af[4], bf[4];
#pragma unroll
        for (int mi = 0; mi < 4; ++mi)
            af[mi] = *(const short8*)&As[(lq * 128 + wm + mi * 16 + lr) * 8];
#pragma unroll
        for (int ni = 0; ni < 4; ++ni)
            bf[ni] = *(const short8*)&Bs[(lq * 128 + wn + ni * 16 + lr) * 8];
#pragma unroll
        for (int mi = 0; mi < 4; ++mi)
#pragma unroll
            for (int ni = 0; ni < 4; ++ni)
                acc[mi][ni] = __builtin_amdgcn_mfma_f32_16x16x32_bf16(
                    af[mi], bf[ni], acc[mi][ni], 0, 0, 0);
    }

#pragma unroll
    for (int mi = 0; mi < 4; ++mi) {
#pragma unroll
        for (int r = 0; r < 4; ++r) {
            int m = mt * 128 + wm + mi * 16 + lq * 4 + r;
            if (m < cnt) {
                ushort_t* hp = h + (size_t)(base + m) * HFF_DIM + nt * 128 + wn + lr;
#pragma unroll
                for (int ni = 0; ni < 4; ++ni)
                    hp[ni * 16] = f2b(gelu_tanh(acc[mi][ni][r]));
            }
        }
    }
}

// GEMM2: out[tok] += gate * (h[slot] . W2b[e]^T). 128x128 tile, BK=32.
__global__ __launch_bounds__(256) void gemm2_fast(
        const ushort_t* __restrict__ h, const ushort_t* __restrict__ W2b,
        const int* __restrict__ count, const int* __restrict__ offsets,
        const int* __restrict__ token_id, const float* __restrict__ gate,
        float* __restrict__ out) {
    const int e = blockIdx.z;
    const int cnt = count[e];
    const int mt = blockIdx.y;
    if (mt * 128 >= cnt) return;
    const int nt = blockIdx.x;
    const int base = offsets[e];

    __shared__ __align__(16) ushort_t As[4096];
    __shared__ __align__(16) ushort_t Bs[4096];

    const int tid = threadIdx.x;
    const int row = tid & 127;
    const int c0 = tid >> 7;

    // h is padded by 128 rows: base+mt*128+row always in-bounds
    const ushort_t* aptr = h + (size_t)(base + mt * 128 + row) * HFF_DIM + c0 * 8;
    const ushort_t* bptr = W2b + (size_t)e * H_DIM * HFF_DIM
                           + (size_t)(nt * 128 + row) * HFF_DIM + c0 * 8;

    ushort_t* aL0 = As + tid * 8;
    ushort_t* aL1 = As + tid * 8 + 2048;
    ushort_t* bL0 = Bs + tid * 8;
    ushort_t* bL1 = Bs + tid * 8 + 2048;

    const int lane = tid & 63;
    const int wave = tid >> 6;
    const int wm = (wave >> 1) << 6;
    const int wn = (wave & 1) << 6;
    const int lr = lane & 15;
    const int lq = lane >> 4;

    f32x4 acc[4][4];
#pragma unroll
    for (int mi = 0; mi < 4; ++mi)
#pragma unroll
        for (int ni = 0; ni < 4; ++ni)
            acc[mi][ni] = (f32x4){0.f, 0.f, 0.f, 0.f};

    for (int k0 = 0; k0 < HFF_DIM; k0 += 32) {
        __syncthreads();
        load_lds16(aptr + k0, aL0);
        load_lds16(aptr + k0 + 16, aL1);
        load_lds16(bptr + k0, bL0);
        load_lds16(bptr + k0 + 16, bL1);
        __syncthreads();

        short8 af[4], bf[4];
#pragma unroll
        for (int mi = 0; mi < 4; ++mi)
            af[mi] = *(const short8*)&As[(lq * 128 + wm + mi * 16 + lr) * 8];
#pragma unroll
        for (int ni = 0; ni < 4; ++ni)
            bf[ni] = *(const short8*)&Bs[(lq * 128 + wn + ni * 16 + lr) * 8];
#pragma unroll
        for (int mi = 0; mi < 4; ++mi)
#pragma unroll
            for (int ni = 0; ni < 4; ++ni)
                acc[mi][ni] = __builtin_amdgcn_mfma_f32_16x16x32_bf16(
                    af[mi], bf[ni], acc[mi][ni], 0, 0, 0);
    }

#pragma unroll
    for (int mi = 0; mi < 4; ++mi) {
#pragma unroll
        for (int r = 0; r < 4; ++r) {
            int m = mt * 128 + wm + mi * 16 + lq * 4 + r;
            if (m < cnt) {
                int tok = token_id[e * TOKENS + m];
                float g = gate[e * TOKENS + m];
                float* op = out + (size_t)tok * H_DIM + nt * 128 + wn + lr;
#pragma unroll
                for (int ni = 0; ni < 4; ++ni)
                    atomicAdd(&op[ni * 16], g * acc[mi][ni][r]);
            }
        }
    }
}

// ================= SLOW PATH (round-1 fallback, f32 on-the-fly) =================
__global__ __launch_bounds__(256) void gemm1_slow(
        const float* __restrict__ x, const float* __restrict__ W1,
        const int* __restrict__ count, const int* __restrict__ offsets,
        const int* __restrict__ token_id, ushort_t* __restrict__ h) {
    const int e = blockIdx.z;
    const int cnt = count[e];
    const int mt = blockIdx.y;
    if (mt * 128 >= cnt) return;
    const int nt = blockIdx.x;
    const int base = offsets[e];

    __shared__ __align__(16) ushort_t As[128 * 32];
    __shared__ __align__(16) ushort_t Bs[128 * 32];

    const int tid = threadIdx.x;
    const int srow = tid >> 1;
    const int scol = (tid & 1) << 4;

    int am = mt * 128 + srow;
    int amc = am < cnt ? am : (cnt - 1);
    const int tok = token_id[e * TOKENS + amc];
    const float* aptr = x + (size_t)tok * H_DIM + scol;
    const float* bptr = W1 + (size_t)e * HFF_DIM * H_DIM
                        + (size_t)(nt * 128 + srow) * H_DIM + scol;

    const int lane = tid & 63;
    const int wave = tid >> 6;
    const int wm = (wave >> 1) << 6;
    const int wn = (wave & 1) << 6;
    const int lr = lane & 15;
    const int lq = lane >> 4;

    f32x4 acc[4][4];
#pragma unroll
    for (int mi = 0; mi < 4; ++mi)
#pragma unroll
        for (int ni = 0; ni < 4; ++ni)
            acc[mi][ni] = (f32x4){0.f, 0.f, 0.f, 0.f};

    for (int k0 = 0; k0 < H_DIM; k0 += 32) {
        ushort_t ta[16], tb[16];
        const float4* pa = (const float4*)(aptr + k0);
        const float4* pb = (const float4*)(bptr + k0);
#pragma unroll
        for (int i = 0; i < 4; ++i) {
            float4 va = pa[i];
            ta[i * 4 + 0] = f2b(va.x); ta[i * 4 + 1] = f2b(va.y);
            ta[i * 4 + 2] = f2b(va.z); ta[i * 4 + 3] = f2b(va.w);
            float4 vb = pb[i];
            tb[i * 4 + 0] = f2b(vb.x); tb[i * 4 + 1] = f2b(vb.y);
            tb[i * 4 + 2] = f2b(vb.z); tb[i * 4 + 3] = f2b(vb.w);
        }
        __syncthreads();
        *(short8*)&As[srow * 32 + scol]     = *(short8*)&ta[0];
        *(short8*)&As[srow * 32 + scol + 8] = *(short8*)&ta[8];
        *(short8*)&Bs[srow * 32 + scol]     = *(short8*)&tb[0];
        *(short8*)&Bs[srow * 32 + scol + 8] = *(short8*)&tb[8];
        __syncthreads();

        short8 af[4], bf[4];
#pragma unroll
        for (int mi = 0; mi < 4; ++mi)
            af[mi] = *(const short8*)&As[(wm + mi * 16 + lr) * 32 + lq * 8];
#pragma unroll
        for (int ni = 0; ni < 4; ++ni)
            bf[ni] = *(const short8*)&Bs[(wn + ni * 16 + lr) * 32 + lq * 8];
#pragma unroll
        for (int mi = 0; mi < 4; ++mi)
#pragma unroll
            for (int ni = 0; ni < 4; ++ni)
                acc[mi][ni] = __builtin_amdgcn_mfma_f32_16x16x32_bf16(
                    af[mi], bf[ni], acc[mi][ni], 0, 0, 0);
    }

#pragma unroll
    for (int mi = 0; mi < 4; ++mi) {
#pragma unroll
        for (int r = 0; r < 4; ++r) {
            int m = mt * 128 + wm + mi * 16 + lq * 4 + r;
            if (m < cnt) {
                ushort_t* hp = h + (size_t)(base + m) * HFF_DIM + nt * 128 + wn + lr;
#pragma unroll
                for (int ni = 0; ni < 4; ++ni)
                    hp[ni * 16] = f2b(gelu_tanh(acc[mi][ni][r]));
            }
        }
    }
}

__global__ __launch_bounds__(256) void gemm2_slow(
        const ushort_t* __restrict__ h, const float* __restrict__ W2,
        const int* __restrict__ count, const int* __restrict__ offsets,
        const int* __restrict__ token_id, const float* __restrict__ gate,
        float* __restrict__ out) {
    const int e = blockIdx.z;
    const int cnt = count[e];
    const int mt = blockIdx.y;
    if (mt * 128 >= cnt) return;
    const int nt = blockIdx.x;
    const int base = offsets[e];

    __shared__ __align__(16) ushort_t As[128 * 32];
    __shared__ __align__(16) ushort_t Bs[128 * 32];

    const int tid = threadIdx.x;
    const int srow = tid >> 1;
    const int scol = (tid & 1) << 4;

    int am = mt * 128 + srow;
    int amc = am < cnt ? am : (cnt - 1);
    const ushort_t* aptr = h + (size_t)(base + amc) * HFF_DIM + scol;
    const float* bptr = W2 + (size_t)e * H_DIM * HFF_DIM
                        + (size_t)(nt * 128 + srow) * HFF_DIM + scol;

    const int lane = tid & 63;
    const int wave = tid >> 6;
    const int wm = (wave >> 1) << 6;
    const int wn = (wave & 1) << 6;
    const int lr = lane & 15;
    const int lq = lane >> 4;

    f32x4 acc[4][4];
#pragma unroll
    for (int mi = 0; mi < 4; ++mi)
#pragma unroll
        for (int ni = 0; ni < 4; ++ni)
            acc[mi][ni] = (f32x4){0.f, 0.f, 0.f, 0.f};

    for (int k0 = 0; k0 < HFF_DIM; k0 += 32) {
        short8 a0 = *(const short8*)(aptr + k0);
        short8 a1 = *(const short8*)(aptr + k0 + 8);
        ushort_t tb[16];
        const float4* pb = (const float4*)(bptr + k0);
#pragma unroll
        for (int i = 0; i < 4; ++i) {
            float4 vb = pb[i];
            tb[i * 4 + 0] = f2b(vb.x); tb[i * 4 + 1] = f2b(vb.y);
            tb[i * 4 + 2] = f2b(vb.z); tb[i * 4 + 3] = f2b(vb.w);
        }
        __syncthreads();
        *(short8*)&As[srow * 32 + scol]     = a0;
        *(short8*)&As[srow * 32 + scol + 8] = a1;
        *(short8*)&Bs[srow * 32 + scol]     = *(short8*)&tb[0];
        *(short8*)&Bs[srow * 32 + scol + 8] = *(short8*)&tb[8];
        __syncthreads();

        short8 af[4], bf[4];
#pragma unroll
        for (int mi = 0; mi < 4; ++mi)
            af[mi] = *(const short8*)&As[(wm + mi * 16 + lr) * 32 + lq * 8];
#pragma unroll
        for (int ni = 0; ni < 4; ++ni)
            bf[ni] = *(const short8*)&Bs[(wn + ni * 16 + lr) * 32 + lq * 8];
#pragma unroll
        for (int mi = 0; mi < 4; ++mi)
#pragma unroll
            for (int ni = 0; ni < 4; ++ni)
                acc[mi][ni] = __builtin_amdgcn_mfma_f32_16x16x32_bf16(
                    af[mi], bf[ni], acc[mi][ni], 0, 0, 0);
    }

#pragma unroll
    for (int mi = 0; mi < 4; ++mi) {
#pragma unroll
        for (int r = 0; r < 4; ++r) {
            int m = mt * 128 + wm + mi * 16 + lq * 4 + r;
            if (m < cnt) {
                int tok = token_id[e * TOKENS + m];
                float g = gate[e * TOKENS + m];
                float* op = out + (size_t)tok * H_DIM + nt * 128 + wn + lr;
#pragma unroll
                for (int ni = 0; ni < 4; ++ni)
                    atomicAdd(&op[ni * 16], g * acc[mi][ni][r]);
            }
        }
    }
}

extern "C" void kernel_launch(void* const* d_in, const int* in_sizes, int n_in,
                              void* d_out, int out_size, void* d_ws, size_t ws_size,
                              hipStream_t stream) {
    const float* x     = (const float*)d_in[0];
    const float* probs = (const float*)d_in[1];
    const int*   idx   = (const int*)d_in[2];
    const float* W1    = (const float*)d_in[3];
    const float* W2    = (const float*)d_in[4];
    float* out = (float*)d_out;

    char* ws = (char*)d_ws;
    int*   count    = (int*)ws;                            // 8 ints
    int*   offsets  = (int*)(ws + 64);                     // 9 ints
    int*   token_id = (int*)(ws + 4096);                   // 128 KB
    float* gate     = (float*)(ws + 4096 + 8 * 4096 * 4);  // 128 KB

    // fast-path layout
    const size_t XB_OFF  = 1ull << 20;                     // 8 MB
    const size_t W1B_OFF = 16ull << 20;                    // 64 MB
    const size_t W2B_OFF = 84ull << 20;                    // 64 MB
    const size_t H_OFF   = 156ull << 20;                   // (8192+128)*4096*2 = 65 MB
    const size_t NEED    = H_OFF + (size_t)(8192 + 128) * HFF_DIM * 2;

    hipMemsetAsync(count, 0, 64, stream);
    hipMemsetAsync(out, 0, (size_t)out_size * sizeof(float), stream);

    route_kernel<<<TOKENS / 256, 256, 0, stream>>>(probs, idx, count, token_id, gate);
    prefix_kernel<<<1, 64, 0, stream>>>(count, offsets);

    if (ws_size >= NEED) {
        ushort_t* xb  = (ushort_t*)(ws + XB_OFF);
        ushort_t* W1b = (ushort_t*)(ws + W1B_OFF);
        ushort_t* W2b = (ushort_t*)(ws + W2B_OFF);
        ushort_t* h   = (ushort_t*)(ws + H_OFF);

        cast_kernel<<<2048, 256, 0, stream>>>(x, xb, TOKENS * H_DIM / 4);
        cast_kernel<<<2048, 256, 0, stream>>>(W1, W1b, NEXP * HFF_DIM * H_DIM / 4);
        cast_kernel<<<2048, 256, 0, stream>>>(W2, W2b, NEXP * H_DIM * HFF_DIM / 4);

        dim3 g1(HFF_DIM / 128, TOKENS / 128, NEXP);
        gemm1_fast<<<g1, 256, 0, stream>>>(xb, W1b, count, offsets, token_id, h);

        dim3 g2(H_DIM / 128, TOKENS / 128, NEXP);
        gemm2_fast<<<g2, 256, 0, stream>>>(h, W2b, count, offsets, token_id, gate, out);
    } else {
        ushort_t* h = (ushort_t*)(ws + (1 << 20));         // 64 MB

        dim3 g1(HFF_DIM / 128, TOKENS / 128, NEXP);
        gemm1_slow<<<g1, 256, 0, stream>>>(x, W1, count, offsets, token_id, h);

        dim3 g2(H_DIM / 128, TOKENS / 128, NEXP);
        gemm2_slow<<<g2, 256, 0, stream>>>(h, W2, count, offsets, token_id, gate, out);
    }
}

// Round 3
// 725.800 us; speedup vs baseline: 1.0571x; 1.0571x over previous
//
#include <hip/hip_runtime.h>

typedef unsigned short ushort_t;
typedef __attribute__((ext_vector_type(4))) ushort_t ushort4_t;
typedef __attribute__((ext_vector_type(8))) short short8;
typedef __attribute__((ext_vector_type(4))) float f32x4;

#define TOKENS  4096
#define H_DIM   1024
#define HFF_DIM 4096
#define NEXP    8

// round-to-nearest-even f32 -> bf16
__device__ __forceinline__ ushort_t f2b(float f) {
    union { float f; unsigned u; } v; v.f = f;
    unsigned r = v.u + 0x7fffu + ((v.u >> 16) & 1u);
    return (ushort_t)(r >> 16);
}

// jax.nn.gelu default: approximate=True (tanh form)
__device__ __forceinline__ float gelu_tanh(float x) {
    float u = 0.7978845608028654f * (x + 0.044715f * x * x * x);
    return 0.5f * x * (1.0f + tanhf(u));
}

// ---------------- routing ----------------
__global__ void route_kernel(const float* __restrict__ probs,
                             const int* __restrict__ idx,
                             int* __restrict__ count,
                             int* __restrict__ token_id,
                             float* __restrict__ gate) {
    int t = blockIdx.x * blockDim.x + threadIdx.x;
    if (t >= TOKENS) return;
    int i0 = idx[t * 2 + 0];
    int i1 = idx[t * 2 + 1];
    float p0 = probs[t * 2 + 0];
    float p1 = probs[t * 2 + 1];
    if (i0 == i1) {
        float p = fmaxf(p0, p1);
        int pos = atomicAdd(&count[i0], 1);
        token_id[i0 * TOKENS + pos] = t;
        gate[i0 * TOKENS + pos] = p;
    } else {
        int pos = atomicAdd(&count[i0], 1);
        token_id[i0 * TOKENS + pos] = t;
        gate[i0 * TOKENS + pos] = p0;
        pos = atomicAdd(&count[i1], 1);
        token_id[i1 * TOKENS + pos] = t;
        gate[i1 * TOKENS + pos] = p1;
    }
}

__global__ void prefix_kernel(const int* __restrict__ count, int* __restrict__ offsets) {
    if (threadIdx.x == 0 && blockIdx.x == 0) {
        int acc = 0;
        for (int e = 0; e < NEXP; ++e) { offsets[e] = acc; acc += count[e]; }
        offsets[NEXP] = acc;
    }
}

// ---------------- fused f32 -> bf16 cast of x, W1, W2 ----------------
__global__ void cast3_kernel(const float* __restrict__ x, ushort_t* __restrict__ xb,
                             const float* __restrict__ W1, ushort_t* __restrict__ W1b,
                             const float* __restrict__ W2, ushort_t* __restrict__ W2b) {
    const int NX = TOKENS * H_DIM / 4;          // float4 counts
    const int NW = NEXP * HFF_DIM * H_DIM / 4;
    const int total = NX + 2 * NW;
    int i = blockIdx.x * blockDim.x + threadIdx.x;
    int stride = gridDim.x * blockDim.x;
    for (; i < total; i += stride) {
        const float4* src; ushort4_t* dst; int j;
        if (i < NX)           { src = (const float4*)x;  dst = (ushort4_t*)xb;  j = i; }
        else if (i < NX + NW) { src = (const float4*)W1; dst = (ushort4_t*)W1b; j = i - NX; }
        else                  { src = (const float4*)W2; dst = (ushort4_t*)W2b; j = i - NX - NW; }
        float4 v = src[j];
        ushort4_t o;
        o.x = f2b(v.x); o.y = f2b(v.y); o.z = f2b(v.z); o.w = f2b(v.w);
        dst[j] = o;
    }
}

// ================= pipelined bf16 GEMMs =================
// LDS tile layout: [c(4 k-chunks of 8)][row(128)][8 bf16] -- bank-conflict-free
// (verified 0 conflicts in R2). K-loop: reg-prefetch k+1, compute k.

// GEMM1: h[slot] = gelu(xb[tok] . W1b[e]^T). 128x128 tile, BK=32, K=1024.
__global__ __launch_bounds__(256) void gemm1_fast(
        const ushort_t* __restrict__ xb, const ushort_t* __restrict__ W1b,
        const int* __restrict__ count, const int* __restrict__ offsets,
        const int* __restrict__ token_id, ushort_t* __restrict__ h) {
    const int e = blockIdx.z;
    const int cnt = count[e];
    const int mt = blockIdx.y;
    if (mt * 128 >= cnt) return;
    const int nt = blockIdx.x;
    const int base = offsets[e];

    __shared__ __align__(16) ushort_t As[4096];  // 8 KB
    __shared__ __align__(16) ushort_t Bs[4096];

    const int tid = threadIdx.x;
    const int row = tid & 127;
    const int c0 = tid >> 7;  // 0..1; second chunk at c0+2

    int am = mt * 128 + row;
    int amc = am < cnt ? am : (cnt - 1);   // clamp: garbage rows discarded in epilogue
    const int tok = token_id[e * TOKENS + amc];
    const ushort_t* aptr = xb + (size_t)tok * H_DIM + c0 * 8;
    const ushort_t* bptr = W1b + (size_t)e * HFF_DIM * H_DIM
                           + (size_t)(nt * 128 + row) * H_DIM + c0 * 8;

    ushort_t* aL0 = As + tid * 8;
    ushort_t* aL1 = As + tid * 8 + 2048;
    ushort_t* bL0 = Bs + tid * 8;
    ushort_t* bL1 = Bs + tid * 8 + 2048;

    const int lane = tid & 63;
    const int wave = tid >> 6;
    const int wm = (wave >> 1) << 6;
    const int wn = (wave & 1) << 6;
    const int lr = lane & 15;
    const int lq = lane >> 4;

    f32x4 acc[4][4];
#pragma unroll
    for (int mi = 0; mi < 4; ++mi)
#pragma unroll
        for (int ni = 0; ni < 4; ++ni)
            acc[mi][ni] = (f32x4){0.f, 0.f, 0.f, 0.f};

    // prologue: fetch k=0 into regs
    short8 ra0 = *(const short8*)(aptr);
    short8 ra1 = *(const short8*)(aptr + 16);
    short8 rb0 = *(const short8*)(bptr);
    short8 rb1 = *(const short8*)(bptr + 16);

    for (int k0 = 0; k0 < H_DIM; k0 += 32) {
        __syncthreads();             // prior iter's ds_reads done
        *(short8*)aL0 = ra0;         // waits vmcnt for this tile's loads
        *(short8*)aL1 = ra1;
        *(short8*)bL0 = rb0;
        *(short8*)bL1 = rb1;
        __syncthreads();

        if (k0 + 32 < H_DIM) {       // prefetch k+1; latency hidden by MFMAs below
            ra0 = *(const short8*)(aptr + k0 + 32);
            ra1 = *(const short8*)(aptr + k0 + 48);
            rb0 = *(const short8*)(bptr + k0 + 32);
            rb1 = *(const short8*)(bptr + k0 + 48);
        }

        short8 af[4], bf[4];
#pragma unroll
        for (int mi = 0; mi < 4; ++mi)
            af[mi] = *(const short8*)&As[(lq * 128 + wm + mi * 16 + lr) * 8];
#pragma unroll
        for (int ni = 0; ni < 4; ++ni)
            bf[ni] = *(const short8*)&Bs[(lq * 128 + wn + ni * 16 + lr) * 8];
#pragma unroll
        for (int mi = 0; mi < 4; ++mi)
#pragma unroll
            for (int ni = 0; ni < 4; ++ni)
                acc[mi][ni] = __builtin_amdgcn_mfma_f32_16x16x32_bf16(
                    af[mi], bf[ni], acc[mi][ni], 0, 0, 0);
    }

#pragma unroll
    for (int mi = 0; mi < 4; ++mi) {
#pragma unroll
        for (int r = 0; r < 4; ++r) {
            int m = mt * 128 + wm + mi * 16 + lq * 4 + r;
            if (m < cnt) {
                ushort_t* hp = h + (size_t)(base + m) * HFF_DIM + nt * 128 + wn + lr;
#pragma unroll
                for (int ni = 0; ni < 4; ++ni)
                    hp[ni * 16] = f2b(gelu_tanh(acc[mi][ni][r]));
            }
        }
    }
}

// GEMM2: out[tok] += gate * (h[slot] . W2b[e]^T). 128x128 tile, BK=32,
// K split into 4 chunks of 1024 (blockIdx.z = e*4+kz) for 4x parallelism.
__global__ __launch_bounds__(256) void gemm2_fast(
        const ushort_t* __restrict__ h, const ushort_t* __restrict__ W2b,
        const int* __restrict__ count, const int* __restrict__ offsets,
        const int* __restrict__ token_id, const float* __restrict__ gate,
        float* __restrict__ out) {
    const int e = blockIdx.z >> 2;
    const int kz = blockIdx.z & 3;
    const int cnt = count[e];
    const int mt = blockIdx.y;
    if (mt * 128 >= cnt) return;
    const int nt = blockIdx.x;
    const int base = offsets[e];
    const int kbeg = kz * (HFF_DIM / 4);
    const int kend = kbeg + (HFF_DIM / 4);

    __shared__ __align__(16) ushort_t As[4096];
    __shared__ __align__(16) ushort_t Bs[4096];

    const int tid = threadIdx.x;
    const int row = tid & 127;
    const int c0 = tid >> 7;

    // h padded by 128 rows: base+mt*128+row always in-bounds
    const ushort_t* aptr = h + (size_t)(base + mt * 128 + row) * HFF_DIM + c0 * 8;
    const ushort_t* bptr = W2b + (size_t)e * H_DIM * HFF_DIM
                           + (size_t)(nt * 128 + row) * HFF_DIM + c0 * 8;

    ushort_t* aL0 = As + tid * 8;
    ushort_t* aL1 = As + tid * 8 + 2048;
    ushort_t* bL0 = Bs + tid * 8;
    ushort_t* bL1 = Bs + tid * 8 + 2048;

    const int lane = tid & 63;
    const int wave = tid >> 6;
    const int wm = (wave >> 1) << 6;
    const int wn = (wave & 1) << 6;
    const int lr = lane & 15;
    const int lq = lane >> 4;

    f32x4 acc[4][4];
#pragma unroll
    for (int mi = 0; mi < 4; ++mi)
#pragma unroll
        for (int ni = 0; ni < 4; ++ni)
            acc[mi][ni] = (f32x4){0.f, 0.f, 0.f, 0.f};

    short8 ra0 = *(const short8*)(aptr + kbeg);
    short8 ra1 = *(const short8*)(aptr + kbeg + 16);
    short8 rb0 = *(const short8*)(bptr + kbeg);
    short8 rb1 = *(const short8*)(bptr + kbeg + 16);

    for (int k0 = kbeg; k0 < kend; k0 += 32) {
        __syncthreads();
        *(short8*)aL0 = ra0;
        *(short8*)aL1 = ra1;
        *(short8*)bL0 = rb0;
        *(short8*)bL1 = rb1;
        __syncthreads();

        if (k0 + 32 < kend) {
            ra0 = *(const short8*)(aptr + k0 + 32);
            ra1 = *(const short8*)(aptr + k0 + 48);
            rb0 = *(const short8*)(bptr + k0 + 32);
            rb1 = *(const short8*)(bptr + k0 + 48);
        }

        short8 af[4], bf[4];
#pragma unroll
        for (int mi = 0; mi < 4; ++mi)
            af[mi] = *(const short8*)&As[(lq * 128 + wm + mi * 16 + lr) * 8];
#pragma unroll
        for (int ni = 0; ni < 4; ++ni)
            bf[ni] = *(const short8*)&Bs[(lq * 128 + wn + ni * 16 + lr) * 8];
#pragma unroll
        for (int mi = 0; mi < 4; ++mi)
#pragma unroll
            for (int ni = 0; ni < 4; ++ni)
                acc[mi][ni] = __builtin_amdgcn_mfma_f32_16x16x32_bf16(
                    af[mi], bf[ni], acc[mi][ni], 0, 0, 0);
    }

#pragma unroll
    for (int mi = 0; mi < 4; ++mi) {
#pragma unroll
        for (int r = 0; r < 4; ++r) {
            int m = mt * 128 + wm + mi * 16 + lq * 4 + r;
            if (m < cnt) {
                int tok = token_id[e * TOKENS + m];
                float g = gate[e * TOKENS + m];
                float* op = out + (size_t)tok * H_DIM + nt * 128 + wn + lr;
#pragma unroll
                for (int ni = 0; ni < 4; ++ni)
                    atomicAdd(&op[ni * 16], g * acc[mi][ni][r]);
            }
        }
    }
}

extern "C" void kernel_launch(void* const* d_in, const int* in_sizes, int n_in,
                              void* d_out, int out_size, void* d_ws, size_t ws_size,
                              hipStream_t stream) {
    const float* x     = (const float*)d_in[0];
    const float* probs = (const float*)d_in[1];
    const int*   idx   = (const int*)d_in[2];
    const float* W1    = (const float*)d_in[3];
    const float* W2    = (const float*)d_in[4];
    float* out = (float*)d_out;

    char* ws = (char*)d_ws;
    int*   count    = (int*)ws;                            // 8 ints
    int*   offsets  = (int*)(ws + 64);                     // 9 ints
    int*   token_id = (int*)(ws + 4096);                   // 128 KB
    float* gate     = (float*)(ws + 4096 + 8 * 4096 * 4);  // 128 KB

    const size_t XB_OFF  = 1ull << 20;                     // 8 MB
    const size_t W1B_OFF = 16ull << 20;                    // 64 MB
    const size_t W2B_OFF = 84ull << 20;                    // 64 MB
    const size_t H_OFF   = 156ull << 20;                   // (8192+128)*4096*2 = 65 MB

    ushort_t* xb  = (ushort_t*)(ws + XB_OFF);
    ushort_t* W1b = (ushort_t*)(ws + W1B_OFF);
    ushort_t* W2b = (ushort_t*)(ws + W2B_OFF);
    ushort_t* h   = (ushort_t*)(ws + H_OFF);

    hipMemsetAsync(count, 0, 64, stream);
    hipMemsetAsync(out, 0, (size_t)out_size * sizeof(float), stream);

    route_kernel<<<TOKENS / 256, 256, 0, stream>>>(probs, idx, count, token_id, gate);
    prefix_kernel<<<1, 64, 0, stream>>>(count, offsets);

    cast3_kernel<<<4096, 256, 0, stream>>>(x, xb, W1, W1b, W2, W2b);

    dim3 g1(HFF_DIM / 128, TOKENS / 128, NEXP);
    gemm1_fast<<<g1, 256, 0, stream>>>(xb, W1b, count, offsets, token_id, h);

    dim3 g2(H_DIM / 128, TOKENS / 128, NEXP * 4);
    gemm2_fast<<<g2, 256, 0, stream>>>(h, W2b, count, offsets, token_id, gate, out);
}